// Round 5
// baseline (249.631 us; speedup 1.0000x reference)
//
#include <hip/hip_runtime.h>
#include <hip/hip_bf16.h>
#include <math.h>

#define NRES 512
#define CS   384
#define CZ   128
#define NH   12
#define PW   1152   // packed projection width: 192*3 + 144*2 + 288

static constexpr float WL_F      = 0.57735026918962576f;   // sqrt(1/3)
static constexpr float HALF_WC_F = 0.11785113019775792f;   // 0.5*sqrt(2/(9*4))

// ---------------------------------------------------------------------------
// Kernel 0: pack 6 weight matrices into Wcat[384][1152].
// ---------------------------------------------------------------------------
__global__ __launch_bounds__(256) void k_pack(
    const float* __restrict__ Wq, const float* __restrict__ Wk,
    const float* __restrict__ Wv, const float* __restrict__ Wqp,
    const float* __restrict__ Wkp, const float* __restrict__ Wvp,
    float* __restrict__ Wcat)
{
    const int c = blockIdx.x;
    for (int col = threadIdx.x; col < PW; col += 256) {
        float v;
        if (col < 192)      v = Wq [(size_t)c * 192 + col];
        else if (col < 384) v = Wk [(size_t)c * 192 + col - 192];
        else if (col < 576) v = Wv [(size_t)c * 192 + col - 384];
        else if (col < 720) v = Wqp[(size_t)c * 144 + col - 576];
        else if (col < 864) v = Wkp[(size_t)c * 144 + col - 720];
        else                v = Wvp[(size_t)c * 288 + col - 864];
        Wcat[(size_t)c * PW + col] = v;
    }
}

// ---------------------------------------------------------------------------
// Kernel 1: P[512][1152] = s @ Wcat, rigid transform fused for cols >= 576.
// BM=32, BN=96, BK=32; grid (12, 16); 256 threads; 2x6 micro-tile.
// ---------------------------------------------------------------------------
__global__ __launch_bounds__(256) void k_gemm(
    const float* __restrict__ s, const float* __restrict__ Wcat,
    const float* __restrict__ rots, const float* __restrict__ trans,
    float* __restrict__ P)
{
    const int tid = threadIdx.x;
    const int tx = tid & 15, ty = tid >> 4;
    const int n0 = blockIdx.x * 96;
    const int m0 = blockIdx.y * 32;
    __shared__ float As[32][34];
    __shared__ float Bs[32][98];
    __shared__ float rot_lds[32][12];

    if (n0 >= 576) {
        for (int idx = tid; idx < 32 * 12; idx += 256) {
            int r = idx / 12, q = idx % 12;
            rot_lds[r][q] = (q < 9) ? rots[(size_t)(m0 + r) * 9 + q]
                                    : trans[(size_t)(m0 + r) * 3 + q - 9];
        }
    }

    float acc[2][6];
    #pragma unroll
    for (int u = 0; u < 2; ++u)
        #pragma unroll
        for (int v = 0; v < 6; ++v) acc[u][v] = 0.f;

    for (int k0 = 0; k0 < CS; k0 += 32) {
        __syncthreads();
        #pragma unroll
        for (int l = 0; l < 4; ++l) {
            int idx = tid + l * 256;
            int kk = idx & 31, r = idx >> 5;
            As[kk][r] = s[(size_t)(m0 + r) * CS + k0 + kk];
        }
        #pragma unroll
        for (int l = 0; l < 12; ++l) {
            int idx = tid + l * 256;
            int kk = idx / 96, cc = idx % 96;
            Bs[kk][cc] = Wcat[(size_t)(k0 + kk) * PW + n0 + cc];
        }
        __syncthreads();
        #pragma unroll
        for (int kk = 0; kk < 32; ++kk) {
            const float2 a  = *(const float2*)&As[kk][ty * 2];
            const float2 b0 = *(const float2*)&Bs[kk][tx * 6];
            const float2 b1 = *(const float2*)&Bs[kk][tx * 6 + 2];
            const float2 b2 = *(const float2*)&Bs[kk][tx * 6 + 4];
            acc[0][0] += a.x * b0.x; acc[0][1] += a.x * b0.y;
            acc[0][2] += a.x * b1.x; acc[0][3] += a.x * b1.y;
            acc[0][4] += a.x * b2.x; acc[0][5] += a.x * b2.y;
            acc[1][0] += a.y * b0.x; acc[1][1] += a.y * b0.y;
            acc[1][2] += a.y * b1.x; acc[1][3] += a.y * b1.y;
            acc[1][4] += a.y * b2.x; acc[1][5] += a.y * b2.y;
        }
    }

    if (n0 >= 576) {
        #pragma unroll
        for (int u = 0; u < 2; ++u) {
            const float* RT = rot_lds[ty * 2 + u];
            #pragma unroll
            for (int v = 0; v < 2; ++v) {
                float p0 = acc[u][v * 3], p1 = acc[u][v * 3 + 1], p2 = acc[u][v * 3 + 2];
                acc[u][v * 3 + 0] = RT[0] * p0 + RT[1] * p1 + RT[2] * p2 + RT[9];
                acc[u][v * 3 + 1] = RT[3] * p0 + RT[4] * p1 + RT[5] * p2 + RT[10];
                acc[u][v * 3 + 2] = RT[6] * p0 + RT[7] * p1 + RT[8] * p2 + RT[11];
            }
        }
    }
    #pragma unroll
    for (int u = 0; u < 2; ++u) {
        float* dst = P + (size_t)(m0 + ty * 2 + u) * PW + n0 + tx * 6;
        *(float2*)(dst)     = make_float2(acc[u][0], acc[u][1]);
        *(float2*)(dst + 2) = make_float2(acc[u][2], acc[u][3]);
        *(float2*)(dst + 4) = make_float2(acc[u][4], acc[u][5]);
    }
}

// ---------------------------------------------------------------------------
// Kernel 2: flash attention chunk. grid (512 i, 4 jc), 256 threads.
// lt[12][132]: transposed prob buffer -> float4 LDS reads everywhere.
// Phase A1: b_ij register-tiled GEMV (thread = 4j x 32c, 8-lane reduce).
// Phase A2: qk + dist2 -> final logits in lt.
// Phase B: softmax (float4, 16 lanes/head). Phase C: float4 prob reads.
// ---------------------------------------------------------------------------
__global__ __launch_bounds__(256) void k_flash(
    const float* __restrict__ z, const float* __restrict__ Wb,
    const float* __restrict__ gamma, const float* __restrict__ P,
    float* __restrict__ part)
{
    const int i   = blockIdx.x;
    const int jc  = blockIdx.y;
    const int j0  = jc * 128;
    const int tid = threadIdx.x;

    __shared__ float q_lds[192];
    __shared__ float qg_lds[144];
    __shared__ float gam_lds[NH];
    __shared__ float pm[NH], ps[NH];
    __shared__ float wbt[NH][CZ];     // [h][c] 6 KB
    __shared__ float lt[NH][132];     // [h][j] 6.3 KB

    const float* qrow = P + (size_t)i * PW;
    if (tid < 192) q_lds[tid]  = qrow[tid];
    if (tid < 144) qg_lds[tid] = qrow[576 + tid];
    for (int idx = tid; idx < NH * CZ; idx += 256) {
        int h = idx >> 7, c = idx & 127;
        wbt[h][c] = Wb[(size_t)c * NH + h];
    }
    if (tid < NH) gam_lds[tid] = gamma[tid];
    __syncthreads();

    // ---- Phase A1: b_ij. thread = (jq 0..31, cq 0..7); 4 j x 32 channels ----
    {
        const int jq = tid >> 3, cq = tid & 7;
        const float4* zb4 = (const float4*)(z + ((size_t)i * NRES + j0 + jq * 4) * CZ);
        float b[4][NH];
        #pragma unroll
        for (int u = 0; u < 4; ++u)
            #pragma unroll
            for (int h = 0; h < NH; ++h) b[u][h] = 0.f;
        #pragma unroll
        for (int qd = 0; qd < 4; ++qd) {
            const int c4 = qd * 8 + cq;           // conflict-free, coalesced
            const float4 z0 = zb4[c4];
            const float4 z1 = zb4[32 + c4];
            const float4 z2 = zb4[64 + c4];
            const float4 z3 = zb4[96 + c4];
            #pragma unroll
            for (int h = 0; h < NH; ++h) {
                const float4 w = *(const float4*)&wbt[h][c4 * 4];
                b[0][h] += z0.x * w.x + z0.y * w.y + z0.z * w.z + z0.w * w.w;
                b[1][h] += z1.x * w.x + z1.y * w.y + z1.z * w.z + z1.w * w.w;
                b[2][h] += z2.x * w.x + z2.y * w.y + z2.z * w.z + z2.w * w.w;
                b[3][h] += z3.x * w.x + z3.y * w.y + z3.z * w.z + z3.w * w.w;
            }
        }
        #pragma unroll
        for (int off = 1; off < 8; off <<= 1)
            #pragma unroll
            for (int u = 0; u < 4; ++u)
                #pragma unroll
                for (int h = 0; h < NH; ++h)
                    b[u][h] += __shfl_xor(b[u][h], off);
        if (cq == 0) {
            #pragma unroll
            for (int u = 0; u < 4; ++u)
                #pragma unroll
                for (int h = 0; h < NH; ++h)
                    lt[h][jq * 4 + u] = b[u][h];
        }
    }
    __syncthreads();

    // ---- Phase A2: qk + dist2 -> logits. thread = (jl, p), 6 heads ----
    {
        const int jl = tid >> 1, p = tid & 1;
        const int j  = j0 + jl;
        const int h0 = p * 6;
        const float* krow  = P + (size_t)j * PW + 192;
        const float* kgrow = P + (size_t)j * PW + 720;
        #pragma unroll
        for (int h3 = 0; h3 < 6; ++h3) {
            const int h = h0 + h3;
            const float4* kp = (const float4*)(krow + h * 16);
            const float4* qp = (const float4*)(q_lds + h * 16);
            float as = 0.f;
            #pragma unroll
            for (int u = 0; u < 4; ++u) {
                float4 kv = kp[u], qv = qp[u];
                as += kv.x * qv.x + kv.y * qv.y + kv.z * qv.z + kv.w * qv.w;
            }
            const float4* kgp = (const float4*)(kgrow + h * 12);
            const float4* qgp = (const float4*)(qg_lds + h * 12);
            float d2 = 0.f;
            #pragma unroll
            for (int u = 0; u < 3; ++u) {
                float4 av = qgp[u], bv = kgp[u];
                float dx = av.x - bv.x, dy = av.y - bv.y;
                float dz = av.z - bv.z, dw = av.w - bv.w;
                d2 += dx * dx + dy * dy + dz * dz + dw * dw;
            }
            const float bv = lt[h][jl];
            lt[h][jl] = WL_F * (as * 0.25f + bv - HALF_WC_F * gam_lds[h] * d2);
        }
    }
    __syncthreads();

    // ---- Phase B: chunk softmax; 16 lanes per head; float4 ----
    if (tid < 192) {
        const int h = tid >> 4, s = tid & 15;
        float4 v0 = *(const float4*)&lt[h][s * 4];
        float4 v1 = *(const float4*)&lt[h][s * 4 + 64];
        float m = fmaxf(fmaxf(fmaxf(v0.x, v0.y), fmaxf(v0.z, v0.w)),
                        fmaxf(fmaxf(v1.x, v1.y), fmaxf(v1.z, v1.w)));
        #pragma unroll
        for (int o = 1; o < 16; o <<= 1) m = fmaxf(m, __shfl_xor(m, o));
        float4 e0, e1;
        e0.x = __expf(v0.x - m); e0.y = __expf(v0.y - m);
        e0.z = __expf(v0.z - m); e0.w = __expf(v0.w - m);
        e1.x = __expf(v1.x - m); e1.y = __expf(v1.y - m);
        e1.z = __expf(v1.z - m); e1.w = __expf(v1.w - m);
        float sum = e0.x + e0.y + e0.z + e0.w + e1.x + e1.y + e1.z + e1.w;
        #pragma unroll
        for (int o = 1; o < 16; o <<= 1) sum += __shfl_xor(sum, o);
        *(float4*)&lt[h][s * 4]      = e0;
        *(float4*)&lt[h][s * 4 + 64] = e1;
        if (s == 0) { pm[h] = m; ps[h] = sum; }
    }
    __syncthreads();

    // ---- Phase C: unnormalized partials; float4 prob reads ----
    float* pb = part + ((size_t)i * 4 + jc) * 2048;
    if (tid < 128) {
        const int g = tid >> 5, u = tid & 31;
        const int h0 = g * 3;
        float4 a0 = {0.f, 0.f, 0.f, 0.f}, a1 = a0, a2 = a0;
        const float4* zb = (const float4*)(z + ((size_t)i * NRES + j0) * CZ);
#define OHAT_STEP(e, comp)                                                  \
        {                                                                   \
            const float4 zv = zb[(q * 4 + e) * 32 + u];                     \
            a0.x += p0.comp * zv.x; a0.y += p0.comp * zv.y;                 \
            a0.z += p0.comp * zv.z; a0.w += p0.comp * zv.w;                 \
            a1.x += p1.comp * zv.x; a1.y += p1.comp * zv.y;                 \
            a1.z += p1.comp * zv.z; a1.w += p1.comp * zv.w;                 \
            a2.x += p2.comp * zv.x; a2.y += p2.comp * zv.y;                 \
            a2.z += p2.comp * zv.z; a2.w += p2.comp * zv.w;                 \
        }
        #pragma unroll 4
        for (int q = 0; q < 32; ++q) {
            const float4 p0 = *(const float4*)&lt[h0][q * 4];
            const float4 p1 = *(const float4*)&lt[h0 + 1][q * 4];
            const float4 p2 = *(const float4*)&lt[h0 + 2][q * 4];
            OHAT_STEP(0, x)
            OHAT_STEP(1, y)
            OHAT_STEP(2, z)
            OHAT_STEP(3, w)
        }
#undef OHAT_STEP
        float4* pb4 = (float4*)pb;
        pb4[(h0 + 0) * 32 + u] = a0;
        pb4[(h0 + 1) * 32 + u] = a1;
        pb4[(h0 + 2) * 32 + u] = a2;
    } else {
        const int t2 = tid - 128;
        if (t2 < 120) {
            int h;
            const float* base;
            if (t2 < 48) { h = t2 >> 2;                  base = P + (size_t)j0 * PW + 384 + t2 * 4; }
            else         { int cc = t2 - 48; h = cc / 6; base = P + (size_t)j0 * PW + 864 + cc * 4; }
            float4 acc = {0.f, 0.f, 0.f, 0.f};
            #pragma unroll 2
            for (int q = 0; q < 32; ++q) {
                const float4 pv = *(const float4*)&lt[h][q * 4];
                const float4 v0 = *(const float4*)(base + (size_t)(q * 4 + 0) * PW);
                const float4 v1 = *(const float4*)(base + (size_t)(q * 4 + 1) * PW);
                const float4 v2 = *(const float4*)(base + (size_t)(q * 4 + 2) * PW);
                const float4 v3 = *(const float4*)(base + (size_t)(q * 4 + 3) * PW);
                acc.x += pv.x * v0.x + pv.y * v1.x + pv.z * v2.x + pv.w * v3.x;
                acc.y += pv.x * v0.y + pv.y * v1.y + pv.z * v2.y + pv.w * v3.y;
                acc.z += pv.x * v0.z + pv.y * v1.z + pv.z * v2.z + pv.w * v3.z;
                acc.w += pv.x * v0.w + pv.y * v1.w + pv.z * v2.w + pv.w * v3.w;
            }
            ((float4*)(pb + 1536))[t2] = acc;
        }
    }
    if (tid < NH) { pb[2016 + tid] = pm[tid]; pb[2028 + tid] = ps[tid]; }
}

// ---------------------------------------------------------------------------
// Kernel 3: combine 4 chunks -> cat row. grid 512, 256 threads.
// ---------------------------------------------------------------------------
__global__ __launch_bounds__(256) void k_combine(
    const float* __restrict__ part, const float* __restrict__ rots,
    const float* __restrict__ trans, float* __restrict__ cat)
{
    const int i   = blockIdx.x;
    const int tid = threadIdx.x;
    __shared__ float wgt[4][NH];
    __shared__ float ohp[288];

    const float* pb = part + (size_t)i * 4 * 2048;
    if (tid < NH) {
        const int h = tid;
        float m0 = pb[2016 + h], m1 = pb[2048 + 2016 + h];
        float m2 = pb[4096 + 2016 + h], m3 = pb[6144 + 2016 + h];
        float M = fmaxf(fmaxf(m0, m1), fmaxf(m2, m3));
        float w0 = __expf(m0 - M), w1 = __expf(m1 - M);
        float w2 = __expf(m2 - M), w3 = __expf(m3 - M);
        float S = w0 * pb[2028 + h] + w1 * pb[2048 + 2028 + h] +
                  w2 * pb[4096 + 2028 + h] + w3 * pb[6144 + 2028 + h];
        float inv = 1.0f / S;
        wgt[0][h] = w0 * inv; wgt[1][h] = w1 * inv;
        wgt[2][h] = w2 * inv; wgt[3][h] = w3 * inv;
    }
    __syncthreads();

    float* crow = cat + (size_t)i * 2112;
    for (int idx = tid; idx < 1536; idx += 256) {
        const int h = idx >> 7;
        float v = 0.f;
        #pragma unroll
        for (int c = 0; c < 4; ++c) v += pb[c * 2048 + idx] * wgt[c][h];
        crow[idx] = v;
    }
    if (tid < 192) {
        const int h = tid >> 4;
        float v = 0.f;
        #pragma unroll
        for (int c = 0; c < 4; ++c) v += pb[c * 2048 + 1536 + tid] * wgt[c][h];
        crow[1536 + tid] = v;
    }
    for (int e = tid; e < 288; e += 256) {
        const int h = e / 24;
        float v = 0.f;
        #pragma unroll
        for (int c = 0; c < 4; ++c) v += pb[c * 2048 + 1728 + e] * wgt[c][h];
        ohp[e] = v;
    }
    __syncthreads();

    if (tid < 96) {
        const int h = tid >> 3, p = tid & 7;
        float R[9];
        #pragma unroll
        for (int k = 0; k < 9; ++k) R[k] = rots[(size_t)i * 9 + k];
        float g0 = ohp[h * 24 + p * 3 + 0] - trans[(size_t)i * 3 + 0];
        float g1 = ohp[h * 24 + p * 3 + 1] - trans[(size_t)i * 3 + 1];
        float g2 = ohp[h * 24 + p * 3 + 2] - trans[(size_t)i * 3 + 2];
        float oy0 = R[0] * g0 + R[3] * g1 + R[6] * g2;
        float oy1 = R[1] * g0 + R[4] * g1 + R[7] * g2;
        float oy2 = R[2] * g0 + R[5] * g1 + R[8] * g2;
        crow[1728 + h * 24 + p * 3 + 0] = oy0;
        crow[1728 + h * 24 + p * 3 + 1] = oy1;
        crow[1728 + h * 24 + p * 3 + 2] = oy2;
        crow[2016 + h * 8 + p] = sqrtf(oy0 * oy0 + oy1 * oy1 + oy2 * oy2);
    }
}

// ---------------------------------------------------------------------------
// Kernel 4: out-proj partials. grid (3 ctile, 64 rtile, 3 ksplit of 704).
// ---------------------------------------------------------------------------
__global__ __launch_bounds__(256) void k_out(
    const float* __restrict__ cat, const float* __restrict__ Wout,
    float* __restrict__ opart)
{
    const int tid = threadIdx.x;
    const int cp  = tid & 63;
    const int qd  = tid >> 6;
    const int c0  = blockIdx.x * 128 + cp * 2;
    const int i0  = blockIdx.y * 8;
    const int k0  = blockIdx.z * 704;
    const int r0  = qd * 2, r1 = r0 + 1;
    __shared__ float lds[8][65];
    float a00 = 0.f, a01 = 0.f, a10 = 0.f, a11 = 0.f;
    for (int kc = k0; kc < k0 + 704; kc += 64) {
        __syncthreads();
        for (int idx = tid; idx < 512; idx += 256) {
            int r = idx >> 6, kk = idx & 63;
            lds[r][kk] = cat[(size_t)(i0 + r) * 2112 + kc + kk];
        }
        __syncthreads();
        #pragma unroll 8
        for (int kk = 0; kk < 64; ++kk) {
            const float2 w = *(const float2*)(Wout + (size_t)(kc + kk) * 384 + c0);
            float l0 = lds[r0][kk], l1 = lds[r1][kk];
            a00 += l0 * w.x; a01 += l0 * w.y;
            a10 += l1 * w.x; a11 += l1 * w.y;
        }
    }
    float* ob = opart + (size_t)blockIdx.z * 512 * 384;
    ob[(size_t)(i0 + r0) * 384 + c0]     = a00;
    ob[(size_t)(i0 + r0) * 384 + c0 + 1] = a01;
    ob[(size_t)(i0 + r1) * 384 + c0]     = a10;
    ob[(size_t)(i0 + r1) * 384 + c0 + 1] = a11;
}

// Kernel 5: reduce 3 k-partials + bias.
__global__ __launch_bounds__(256) void k_outred(
    const float* __restrict__ opart, const float* __restrict__ bout,
    float* __restrict__ out)
{
    const int e4 = blockIdx.x * 256 + threadIdx.x;
    const float4* p = (const float4*)opart;
    const float4 b = ((const float4*)bout)[e4 % 96];
    float4 v0 = p[e4], v1 = p[e4 + 49152], v2 = p[e4 + 98304];
    float4 r;
    r.x = v0.x + v1.x + v2.x + b.x;
    r.y = v0.y + v1.y + v2.y + b.y;
    r.z = v0.z + v1.z + v2.z + b.z;
    r.w = v0.w + v1.w + v2.w + b.w;
    ((float4*)out)[e4] = r;
}

// ---------------------------------------------------------------------------
extern "C" void kernel_launch(void* const* d_in, const int* in_sizes, int n_in,
                              void* d_out, int out_size, void* d_ws, size_t ws_size,
                              hipStream_t stream)
{
    const float* s_i   = (const float*)d_in[0];
    const float* z_ij  = (const float*)d_in[1];
    const float* rots  = (const float*)d_in[2];
    const float* trans = (const float*)d_in[3];
    const float* Wq    = (const float*)d_in[4];
    const float* Wk    = (const float*)d_in[5];
    const float* Wv    = (const float*)d_in[6];
    const float* Wqp   = (const float*)d_in[7];
    const float* Wkp   = (const float*)d_in[8];
    const float* Wvp   = (const float*)d_in[9];
    const float* Wb    = (const float*)d_in[10];
    const float* gamma = (const float*)d_in[11];
    const float* Wout  = (const float*)d_in[12];
    const float* bout  = (const float*)d_in[13];
    float* ws = (float*)d_ws;
    float* wcat  = ws;                  // aliased with opart (sequenced)
    float* opart = ws;
    float* P     = ws + 589824;         // 512*1152
    float* part  = P + 589824;          // 512*4*2048
    float* cat   = part + 4194304;      // 512*2112
    float* out   = (float*)d_out;

    hipLaunchKernelGGL(k_pack, dim3(384), dim3(256), 0, stream,
                       Wq, Wk, Wv, Wqp, Wkp, Wvp, wcat);
    hipLaunchKernelGGL(k_gemm, dim3(12, 16), dim3(256), 0, stream,
                       s_i, wcat, rots, trans, P);
    hipLaunchKernelGGL(k_flash, dim3(512, 4), dim3(256), 0, stream,
                       z_ij, Wb, gamma, P, part);
    hipLaunchKernelGGL(k_combine, dim3(512), dim3(256), 0, stream,
                       part, rots, trans, cat);
    hipLaunchKernelGGL(k_out, dim3(3, 64, 3), dim3(256), 0, stream,
                       cat, Wout, opart);
    hipLaunchKernelGGL(k_outred, dim3(192), dim3(256), 0, stream,
                       opart, bout, out);
}

// Round 6
// 204.442 us; speedup vs baseline: 1.2210x; 1.2210x over previous
//
#include <hip/hip_runtime.h>
#include <hip/hip_bf16.h>
#include <math.h>

#define NRES 512
#define CS   384
#define CZ   128
#define NH   12
#define PW   1152   // packed projection width
#define JB   64     // j per flash block
#define NCH  8      // chunks = NRES/JB
#define PSTRIDE32 1040  // part chunk stride in u32 units

static constexpr float WL_F      = 0.57735026918962576f;   // sqrt(1/3)
static constexpr float HALF_WC_F = 0.11785113019775792f;   // 0.5*sqrt(2/(9*4))

typedef __attribute__((ext_vector_type(8))) short short8v;
typedef __attribute__((ext_vector_type(4))) float floatx4;

__device__ __forceinline__ ushort f2b(float f) {
    union { float f; uint u; } v; v.f = f;
    return (ushort)((v.u + 0x7FFFu + ((v.u >> 16) & 1u)) >> 16);
}
__device__ __forceinline__ float b2f(ushort b) {
    union { uint u; float f; } v; v.u = ((uint)b) << 16; return v.f;
}

// ---------------------------------------------------------------------------
// Kernel 0: pack 6 weight matrices into Wcat[384][1152].
// ---------------------------------------------------------------------------
__global__ __launch_bounds__(256) void k_pack(
    const float* __restrict__ Wq, const float* __restrict__ Wk,
    const float* __restrict__ Wv, const float* __restrict__ Wqp,
    const float* __restrict__ Wkp, const float* __restrict__ Wvp,
    float* __restrict__ Wcat)
{
    const int c = blockIdx.x;
    for (int col = threadIdx.x; col < PW; col += 256) {
        float v;
        if (col < 192)      v = Wq [(size_t)c * 192 + col];
        else if (col < 384) v = Wk [(size_t)c * 192 + col - 192];
        else if (col < 576) v = Wv [(size_t)c * 192 + col - 384];
        else if (col < 720) v = Wqp[(size_t)c * 144 + col - 576];
        else if (col < 864) v = Wkp[(size_t)c * 144 + col - 720];
        else                v = Wvp[(size_t)c * 288 + col - 864];
        Wcat[(size_t)c * PW + col] = v;
    }
}

// ---------------------------------------------------------------------------
// Kernel 1: P[512][1152] = s @ Wcat, rigid transform fused for cols >= 576.
// ---------------------------------------------------------------------------
__global__ __launch_bounds__(256) void k_gemm(
    const float* __restrict__ s, const float* __restrict__ Wcat,
    const float* __restrict__ rots, const float* __restrict__ trans,
    float* __restrict__ P)
{
    const int tid = threadIdx.x;
    const int tx = tid & 15, ty = tid >> 4;
    const int n0 = blockIdx.x * 96;
    const int m0 = blockIdx.y * 32;
    __shared__ float As[32][34];
    __shared__ float Bs[32][98];
    __shared__ float rot_lds[32][12];

    if (n0 >= 576) {
        for (int idx = tid; idx < 32 * 12; idx += 256) {
            int r = idx / 12, q = idx % 12;
            rot_lds[r][q] = (q < 9) ? rots[(size_t)(m0 + r) * 9 + q]
                                    : trans[(size_t)(m0 + r) * 3 + q - 9];
        }
    }

    float acc[2][6];
    #pragma unroll
    for (int u = 0; u < 2; ++u)
        #pragma unroll
        for (int v = 0; v < 6; ++v) acc[u][v] = 0.f;

    for (int k0 = 0; k0 < CS; k0 += 32) {
        __syncthreads();
        #pragma unroll
        for (int l = 0; l < 4; ++l) {
            int idx = tid + l * 256;
            int kk = idx & 31, r = idx >> 5;
            As[kk][r] = s[(size_t)(m0 + r) * CS + k0 + kk];
        }
        #pragma unroll
        for (int l = 0; l < 12; ++l) {
            int idx = tid + l * 256;
            int kk = idx / 96, cc = idx % 96;
            Bs[kk][cc] = Wcat[(size_t)(k0 + kk) * PW + n0 + cc];
        }
        __syncthreads();
        #pragma unroll
        for (int kk = 0; kk < 32; ++kk) {
            const float2 a  = *(const float2*)&As[kk][ty * 2];
            const float2 b0 = *(const float2*)&Bs[kk][tx * 6];
            const float2 b1 = *(const float2*)&Bs[kk][tx * 6 + 2];
            const float2 b2 = *(const float2*)&Bs[kk][tx * 6 + 4];
            acc[0][0] += a.x * b0.x; acc[0][1] += a.x * b0.y;
            acc[0][2] += a.x * b1.x; acc[0][3] += a.x * b1.y;
            acc[0][4] += a.x * b2.x; acc[0][5] += a.x * b2.y;
            acc[1][0] += a.y * b0.x; acc[1][1] += a.y * b0.y;
            acc[1][2] += a.y * b1.x; acc[1][3] += a.y * b1.y;
            acc[1][4] += a.y * b2.x; acc[1][5] += a.y * b2.y;
        }
    }

    if (n0 >= 576) {
        #pragma unroll
        for (int u = 0; u < 2; ++u) {
            const float* RT = rot_lds[ty * 2 + u];
            #pragma unroll
            for (int v = 0; v < 2; ++v) {
                float p0 = acc[u][v * 3], p1 = acc[u][v * 3 + 1], p2 = acc[u][v * 3 + 2];
                acc[u][v * 3 + 0] = RT[0] * p0 + RT[1] * p1 + RT[2] * p2 + RT[9];
                acc[u][v * 3 + 1] = RT[3] * p0 + RT[4] * p1 + RT[5] * p2 + RT[10];
                acc[u][v * 3 + 2] = RT[6] * p0 + RT[7] * p1 + RT[8] * p2 + RT[11];
            }
        }
    }
    #pragma unroll
    for (int u = 0; u < 2; ++u) {
        float* dst = P + (size_t)(m0 + ty * 2 + u) * PW + n0 + tx * 6;
        *(float2*)(dst)     = make_float2(acc[u][0], acc[u][1]);
        *(float2*)(dst + 2) = make_float2(acc[u][2], acc[u][3]);
        *(float2*)(dst + 4) = make_float2(acc[u][4], acc[u][5]);
    }
}

// ---------------------------------------------------------------------------
// Kernel 2: MFMA flash chunk. grid (512 i, 8 jc), 256 threads (4 waves).
// z tile (64j x 128c) staged ONCE to LDS as bf16 in two orientations:
//   zb [j][c]  (A-operand of b_ij GEMM), 16-B-unit swizzle u^(j&15)
//   zbT[d][j]  (B-operand of o_hat GEMM), swizzle u^(d&7)
// b_ij via mfma 16x16x32 (4 M-tiles x 4 K); logits += qk/dist2 (vector);
// chunk softmax; o_hat via mfma (8 N-tiles x 2 K, waves 0-1) while
// waves 2-3 do o/o_hp vector from P. Partials stored bf16.
// part chunk (u32 stride 1040): u16[0,1536) ohat | [1536,1728) o |
// [1728,2016) ohp ; f32 @u32 1008+h = pm, 1020+h = ps.
// ---------------------------------------------------------------------------
__global__ __launch_bounds__(256) void k_flash(
    const float* __restrict__ z, const float* __restrict__ Wb,
    const float* __restrict__ gamma, const float* __restrict__ P,
    uint* __restrict__ part)
{
    const int i   = blockIdx.x;
    const int jc  = blockIdx.y;
    const int j0  = jc * JB;
    const int tid = threadIdx.x;
    const int wid = tid >> 6, lane = tid & 63;

    __shared__ __align__(16) short zb [JB * 128];    // 16 KB
    __shared__ __align__(16) short zbT[128 * JB];    // 16 KB
    __shared__ __align__(16) short wbT[16 * 128];    // 4 KB
    __shared__ __align__(16) short ltb[16 * 64];     // 2 KB
    __shared__ float ltf[16 * 68];                   // 4.35 KB
    __shared__ float q_lds[192];
    __shared__ float qg_lds[144];
    __shared__ float gam_lds[NH];

    uint* pb32   = part + ((size_t)i * NCH + jc) * PSTRIDE32;
    ushort* pb16 = (ushort*)pb32;
    float* pbf   = (float*)pb32;

    // ---- staging ----
    {
        const float* qrow = P + (size_t)i * PW;
        if (tid < 192) q_lds[tid]  = qrow[tid];
        if (tid < 144) qg_lds[tid] = qrow[576 + tid];
        if (tid < NH)  gam_lds[tid] = gamma[tid];

        // wbT[h][c] bf16, rows 12..15 zero. thread: h=tid&15, u=tid>>4.
        {
            const int h = tid & 15, u = tid >> 4;
            short8v s;
            #pragma unroll
            for (int e = 0; e < 8; ++e) {
                const int c = u * 8 + e;
                s[e] = (h < NH) ? (short)f2b(Wb[(size_t)c * NH + h]) : (short)0;
            }
            *(short8v*)&wbT[h * 128 + ((u ^ (h & 7)) * 8)] = s;
        }

        // z tile: thread = (jlane = lane, dgrp = wid): 32 channels.
        const float4* zr = (const float4*)(z + ((size_t)i * NRES + j0 + lane) * CZ + wid * 32);
        float f[32];
        #pragma unroll
        for (int k = 0; k < 8; ++k) {
            const float4 t = zr[k];
            f[k * 4 + 0] = t.x; f[k * 4 + 1] = t.y;
            f[k * 4 + 2] = t.z; f[k * 4 + 3] = t.w;
        }
        #pragma unroll
        for (int k = 0; k < 4; ++k) {
            short8v s;
            #pragma unroll
            for (int e = 0; e < 8; ++e) s[e] = (short)f2b(f[k * 8 + e]);
            const int u = wid * 4 + k;
            *(short8v*)&zb[lane * 128 + ((u ^ (lane & 15)) * 8)] = s;
        }
        #pragma unroll
        for (int m = 0; m < 32; ++m) {
            const int c = wid * 32 + m;
            zbT[c * 64 + (((lane >> 3) ^ (c & 7)) * 8) + (lane & 7)] = (short)f2b(f[m]);
        }
    }
    __syncthreads();

    // ---- b_ij MFMA: wave w = M-tile w (16 j), K=128 (4 steps) ----
    {
        const int jrow = wid * 16 + (lane & 15);
        const int hcol = lane & 15;
        floatx4 acc = {0.f, 0.f, 0.f, 0.f};
        #pragma unroll
        for (int ks = 0; ks < 4; ++ks) {
            const int u = (lane >> 4) + ks * 4;
            const short8v a = *(const short8v*)&zb[jrow * 128 + ((u ^ (jrow & 15)) * 8)];
            const short8v b = *(const short8v*)&wbT[hcol * 128 + ((u ^ (hcol & 7)) * 8)];
            acc = __builtin_amdgcn_mfma_f32_16x16x32_bf16(a, b, acc, 0, 0, 0);
        }
        #pragma unroll
        for (int r = 0; r < 4; ++r)
            ltf[hcol * 68 + wid * 16 + (lane >> 4) * 4 + r] = acc[r];
    }
    __syncthreads();

    // ---- logits: qk + dist2. thread = (jl = tid&63, hg = tid>>6): 3 heads ----
    {
        const int jl = tid & 63;
        const int j  = j0 + jl;
        const float* krow  = P + (size_t)j * PW + 192;
        const float* kgrow = P + (size_t)j * PW + 720;
        #pragma unroll
        for (int h3 = 0; h3 < 3; ++h3) {
            const int h = wid * 3 + h3;
            const float4* kp = (const float4*)(krow + h * 16);
            const float4* qp = (const float4*)(q_lds + h * 16);
            float as = 0.f;
            #pragma unroll
            for (int u = 0; u < 4; ++u) {
                const float4 kv = kp[u], qv = qp[u];
                as += kv.x * qv.x + kv.y * qv.y + kv.z * qv.z + kv.w * qv.w;
            }
            const float4* kgp = (const float4*)(kgrow + h * 12);
            const float4* qgp = (const float4*)(qg_lds + h * 12);
            float d2 = 0.f;
            #pragma unroll
            for (int u = 0; u < 3; ++u) {
                const float4 av = qgp[u], bv = kgp[u];
                const float dx = av.x - bv.x, dy = av.y - bv.y;
                const float dz = av.z - bv.z, dw = av.w - bv.w;
                d2 += dx * dx + dy * dy + dz * dz + dw * dw;
            }
            const float bij = ltf[h * 68 + jl];
            ltf[h * 68 + jl] = WL_F * (as * 0.25f + bij - HALF_WC_F * gam_lds[h] * d2);
        }
    }
    __syncthreads();

    // ---- chunk softmax (16 lanes/head) + bf16 prob write ----
    if (tid < 192) {
        const int h = tid >> 4, s = tid & 15;
        float4 v = *(const float4*)&ltf[h * 68 + s * 4];
        float m = fmaxf(fmaxf(v.x, v.y), fmaxf(v.z, v.w));
        #pragma unroll
        for (int o = 1; o < 16; o <<= 1) m = fmaxf(m, __shfl_xor(m, o));
        float4 e;
        e.x = __expf(v.x - m); e.y = __expf(v.y - m);
        e.z = __expf(v.z - m); e.w = __expf(v.w - m);
        float sum = e.x + e.y + e.z + e.w;
        #pragma unroll
        for (int o = 1; o < 16; o <<= 1) sum += __shfl_xor(sum, o);
        *(float4*)&ltf[h * 68 + s * 4] = e;
        const uint lo = (uint)f2b(e.x) | ((uint)f2b(e.y) << 16);
        const uint hi = (uint)f2b(e.z) | ((uint)f2b(e.w) << 16);
        uint* dst = (uint*)&ltb[h * 64 + (((s >> 1) ^ (h & 7)) * 8) + (s & 1) * 4];
        dst[0] = lo; dst[1] = hi;
        if (s == 0) { pbf[1008 + h] = m; pbf[1020 + h] = sum; }
    } else {
        // zero ltb pad rows 12..15
        const int tt = tid - 192;
        uint* dst = (uint*)&ltb[(12 + (tt >> 4)) * 64 + (tt & 15) * 4];
        dst[0] = 0u; dst[1] = 0u;
    }
    __syncthreads();

    // ---- waves 0-1: o_hat MFMA (M=16h, N=128d, K=64j). wave w: N-tiles 4w.. ----
    if (wid < 2) {
        const int hrow = lane & 15;
        const int u0 = (lane >> 4), u1 = (lane >> 4) + 4;
        const short8v a0 = *(const short8v*)&ltb[hrow * 64 + ((u0 ^ (hrow & 7)) * 8)];
        const short8v a1 = *(const short8v*)&ltb[hrow * 64 + ((u1 ^ (hrow & 7)) * 8)];
        #pragma unroll
        for (int t = 0; t < 4; ++t) {
            const int nt = wid * 4 + t;
            const int d  = nt * 16 + (lane & 15);
            const short8v b0 = *(const short8v*)&zbT[d * 64 + ((u0 ^ (d & 7)) * 8)];
            const short8v b1 = *(const short8v*)&zbT[d * 64 + ((u1 ^ (d & 7)) * 8)];
            floatx4 acc = {0.f, 0.f, 0.f, 0.f};
            acc = __builtin_amdgcn_mfma_f32_16x16x32_bf16(a0, b0, acc, 0, 0, 0);
            acc = __builtin_amdgcn_mfma_f32_16x16x32_bf16(a1, b1, acc, 0, 0, 0);
            #pragma unroll
            for (int r = 0; r < 4; ++r) {
                const int h = (lane >> 4) * 4 + r;
                if (h < NH) pb16[h * 128 + d] = f2b(acc[r]);
            }
        }
    } else {
        // ---- waves 2-3: o / o_hp vector from P (unnormalized e in ltf) ----
        const int t2 = tid - 128;
        if (t2 < 120) {
            int h, off16;
            const float* base;
            if (t2 < 48) { h = t2 >> 2; base = P + (size_t)j0 * PW + 384 + t2 * 4; off16 = 1536 + t2 * 4; }
            else { const int cc = t2 - 48; h = cc / 6; base = P + (size_t)j0 * PW + 864 + cc * 4; off16 = 1728 + cc * 4; }
            float ax = 0.f, ay = 0.f, az = 0.f, aw = 0.f;
            #pragma unroll 4
            for (int jj = 0; jj < JB; ++jj) {
                const float e = ltf[h * 68 + jj];
                const float4 v = *(const float4*)(base + (size_t)jj * PW);
                ax += e * v.x; ay += e * v.y; az += e * v.z; aw += e * v.w;
            }
            uint* dst = (uint*)&pb16[off16];
            dst[0] = (uint)f2b(ax) | ((uint)f2b(ay) << 16);
            dst[1] = (uint)f2b(az) | ((uint)f2b(aw) << 16);
        }
    }
}

// ---------------------------------------------------------------------------
// Kernel 3: combine 8 chunks -> cat row. grid 512, 256 threads.
// ---------------------------------------------------------------------------
__global__ __launch_bounds__(256) void k_combine(
    const uint* __restrict__ part, const float* __restrict__ rots,
    const float* __restrict__ trans, float* __restrict__ cat)
{
    const int i   = blockIdx.x;
    const int tid = threadIdx.x;
    __shared__ float wgt[NCH][NH];
    __shared__ float ohp[288];

    const uint* base = part + (size_t)i * NCH * PSTRIDE32;
    if (tid < NH) {
        const int h = tid;
        float mm[NCH];
        float M = -1e30f;
        #pragma unroll
        for (int c = 0; c < NCH; ++c) {
            mm[c] = ((const float*)(base + c * PSTRIDE32))[1008 + h];
            M = fmaxf(M, mm[c]);
        }
        float S = 0.f;
        #pragma unroll
        for (int c = 0; c < NCH; ++c) {
            const float w = __expf(mm[c] - M);
            S += w * ((const float*)(base + c * PSTRIDE32))[1020 + h];
            wgt[c][h] = w;
        }
        const float inv = 1.0f / S;
        #pragma unroll
        for (int c = 0; c < NCH; ++c) wgt[c][h] *= inv;
    }
    __syncthreads();

    float* crow = cat + (size_t)i * 2112;
    for (int idx = tid; idx < 1536; idx += 256) {
        const int h = idx >> 7;
        float v = 0.f;
        #pragma unroll
        for (int c = 0; c < NCH; ++c)
            v += b2f(((const ushort*)(base + c * PSTRIDE32))[idx]) * wgt[c][h];
        crow[idx] = v;
    }
    if (tid < 192) {
        const int h = tid >> 4;
        float v = 0.f;
        #pragma unroll
        for (int c = 0; c < NCH; ++c)
            v += b2f(((const ushort*)(base + c * PSTRIDE32))[1536 + tid]) * wgt[c][h];
        crow[1536 + tid] = v;
    }
    for (int e = tid; e < 288; e += 256) {
        const int h = e / 24;
        float v = 0.f;
        #pragma unroll
        for (int c = 0; c < NCH; ++c)
            v += b2f(((const ushort*)(base + c * PSTRIDE32))[1728 + e]) * wgt[c][h];
        ohp[e] = v;
    }
    __syncthreads();

    if (tid < 96) {
        const int h = tid >> 3, p = tid & 7;
        float R[9];
        #pragma unroll
        for (int k = 0; k < 9; ++k) R[k] = rots[(size_t)i * 9 + k];
        const float g0 = ohp[h * 24 + p * 3 + 0] - trans[(size_t)i * 3 + 0];
        const float g1 = ohp[h * 24 + p * 3 + 1] - trans[(size_t)i * 3 + 1];
        const float g2 = ohp[h * 24 + p * 3 + 2] - trans[(size_t)i * 3 + 2];
        const float oy0 = R[0] * g0 + R[3] * g1 + R[6] * g2;
        const float oy1 = R[1] * g0 + R[4] * g1 + R[7] * g2;
        const float oy2 = R[2] * g0 + R[5] * g1 + R[8] * g2;
        crow[1728 + h * 24 + p * 3 + 0] = oy0;
        crow[1728 + h * 24 + p * 3 + 1] = oy1;
        crow[1728 + h * 24 + p * 3 + 2] = oy2;
        crow[2016 + h * 8 + p] = sqrtf(oy0 * oy0 + oy1 * oy1 + oy2 * oy2);
    }
}

// ---------------------------------------------------------------------------
// Kernel 4: out-proj partials. grid (3 ctile, 64 rtile, 3 ksplit of 704).
// ---------------------------------------------------------------------------
__global__ __launch_bounds__(256) void k_out(
    const float* __restrict__ cat, const float* __restrict__ Wout,
    float* __restrict__ opart)
{
    const int tid = threadIdx.x;
    const int cp  = tid & 63;
    const int qd  = tid >> 6;
    const int c0  = blockIdx.x * 128 + cp * 2;
    const int i0  = blockIdx.y * 8;
    const int k0  = blockIdx.z * 704;
    const int r0  = qd * 2, r1 = r0 + 1;
    __shared__ float lds[8][65];
    float a00 = 0.f, a01 = 0.f, a10 = 0.f, a11 = 0.f;
    for (int kc = k0; kc < k0 + 704; kc += 64) {
        __syncthreads();
        for (int idx = tid; idx < 512; idx += 256) {
            int r = idx >> 6, kk = idx & 63;
            lds[r][kk] = cat[(size_t)(i0 + r) * 2112 + kc + kk];
        }
        __syncthreads();
        #pragma unroll 8
        for (int kk = 0; kk < 64; ++kk) {
            const float2 w = *(const float2*)(Wout + (size_t)(kc + kk) * 384 + c0);
            float l0 = lds[r0][kk], l1 = lds[r1][kk];
            a00 += l0 * w.x; a01 += l0 * w.y;
            a10 += l1 * w.x; a11 += l1 * w.y;
        }
    }
    float* ob = opart + (size_t)blockIdx.z * 512 * 384;
    ob[(size_t)(i0 + r0) * 384 + c0]     = a00;
    ob[(size_t)(i0 + r0) * 384 + c0 + 1] = a01;
    ob[(size_t)(i0 + r1) * 384 + c0]     = a10;
    ob[(size_t)(i0 + r1) * 384 + c0 + 1] = a11;
}

// Kernel 5: reduce 3 k-partials + bias.
__global__ __launch_bounds__(256) void k_outred(
    const float* __restrict__ opart, const float* __restrict__ bout,
    float* __restrict__ out)
{
    const int e4 = blockIdx.x * 256 + threadIdx.x;
    const float4* p = (const float4*)opart;
    const float4 b = ((const float4*)bout)[e4 % 96];
    float4 v0 = p[e4], v1 = p[e4 + 49152], v2 = p[e4 + 98304];
    float4 r;
    r.x = v0.x + v1.x + v2.x + b.x;
    r.y = v0.y + v1.y + v2.y + b.y;
    r.z = v0.z + v1.z + v2.z + b.z;
    r.w = v0.w + v1.w + v2.w + b.w;
    ((float4*)out)[e4] = r;
}

// ---------------------------------------------------------------------------
extern "C" void kernel_launch(void* const* d_in, const int* in_sizes, int n_in,
                              void* d_out, int out_size, void* d_ws, size_t ws_size,
                              hipStream_t stream)
{
    const float* s_i   = (const float*)d_in[0];
    const float* z_ij  = (const float*)d_in[1];
    const float* rots  = (const float*)d_in[2];
    const float* trans = (const float*)d_in[3];
    const float* Wq    = (const float*)d_in[4];
    const float* Wk    = (const float*)d_in[5];
    const float* Wv    = (const float*)d_in[6];
    const float* Wqp   = (const float*)d_in[7];
    const float* Wkp   = (const float*)d_in[8];
    const float* Wvp   = (const float*)d_in[9];
    const float* Wb    = (const float*)d_in[10];
    const float* gamma = (const float*)d_in[11];
    const float* Wout  = (const float*)d_in[12];
    const float* bout  = (const float*)d_in[13];
    float* ws = (float*)d_ws;
    float* wcat  = ws;                   // aliased with opart (sequenced)
    float* opart = ws;
    float* P     = ws + 589824;          // 512*1152
    uint*  part  = (uint*)(P + 589824);  // 512*8*1040 u32 = 17 MB
    float* cat   = (float*)part + (size_t)512 * NCH * PSTRIDE32;  // 512*2112
    float* out   = (float*)d_out;

    hipLaunchKernelGGL(k_pack, dim3(384), dim3(256), 0, stream,
                       Wq, Wk, Wv, Wqp, Wkp, Wvp, wcat);
    hipLaunchKernelGGL(k_gemm, dim3(12, 16), dim3(256), 0, stream,
                       s_i, wcat, rots, trans, P);
    hipLaunchKernelGGL(k_flash, dim3(512, NCH), dim3(256), 0, stream,
                       z_ij, Wb, gamma, P, part);
    hipLaunchKernelGGL(k_combine, dim3(512), dim3(256), 0, stream,
                       part, rots, trans, cat);
    hipLaunchKernelGGL(k_out, dim3(3, 64, 3), dim3(256), 0, stream,
                       cat, Wout, opart);
    hipLaunchKernelGGL(k_outred, dim3(192), dim3(256), 0, stream,
                       opart, bout, out);
}

// Round 7
// 202.416 us; speedup vs baseline: 1.2333x; 1.0100x over previous
//
#include <hip/hip_runtime.h>
#include <hip/hip_bf16.h>
#include <math.h>

#define NRES 512
#define CS   384
#define CZ   128
#define NH   12
#define PW   1152   // packed projection width
#define JB   64     // j per flash block
#define NCH  8      // chunks = NRES/JB
#define PSTRIDE32 1040  // part chunk stride in u32 units
#define KSPLIT 11   // k_out K splits (2112 = 11*192)

static constexpr float WL_F      = 0.57735026918962576f;   // sqrt(1/3)
static constexpr float HALF_WC_F = 0.11785113019775792f;   // 0.5*sqrt(2/(9*4))

typedef __attribute__((ext_vector_type(8))) short short8v;
typedef __attribute__((ext_vector_type(4))) float floatx4;

__device__ __forceinline__ ushort f2b(float f) {
    union { float f; uint u; } v; v.f = f;
    return (ushort)((v.u + 0x7FFFu + ((v.u >> 16) & 1u)) >> 16);
}
__device__ __forceinline__ float b2f(ushort b) {
    union { uint u; float f; } v; v.u = ((uint)b) << 16; return v.f;
}

// ---------------------------------------------------------------------------
// Kernel 0: pack 6 weight matrices into Wcat[384][1152]; block 0 also packs
// WbT16[16][128] bf16 (rows >= 12 zero) for direct global B-fragment reads.
// ---------------------------------------------------------------------------
__global__ __launch_bounds__(256) void k_pack(
    const float* __restrict__ Wq, const float* __restrict__ Wk,
    const float* __restrict__ Wv, const float* __restrict__ Wqp,
    const float* __restrict__ Wkp, const float* __restrict__ Wvp,
    const float* __restrict__ Wb,
    float* __restrict__ Wcat, ushort* __restrict__ wbt16)
{
    const int c = blockIdx.x;
    for (int col = threadIdx.x; col < PW; col += 256) {
        float v;
        if (col < 192)      v = Wq [(size_t)c * 192 + col];
        else if (col < 384) v = Wk [(size_t)c * 192 + col - 192];
        else if (col < 576) v = Wv [(size_t)c * 192 + col - 384];
        else if (col < 720) v = Wqp[(size_t)c * 144 + col - 576];
        else if (col < 864) v = Wkp[(size_t)c * 144 + col - 720];
        else                v = Wvp[(size_t)c * 288 + col - 864];
        Wcat[(size_t)c * PW + col] = v;
    }
    if (blockIdx.x == 0) {
        for (int idx = threadIdx.x; idx < 16 * 128; idx += 256) {
            const int h = idx >> 7, cc = idx & 127;
            wbt16[idx] = (h < NH) ? f2b(Wb[(size_t)cc * NH + h]) : (ushort)0;
        }
    }
}

// ---------------------------------------------------------------------------
// Kernel 1: P[512][1152] = s @ Wcat, rigid transform fused for cols >= 576.
// BM=32, BN=48; grid (24, 16); 256 threads; 2x3 micro-tile.
// ---------------------------------------------------------------------------
__global__ __launch_bounds__(256) void k_gemm(
    const float* __restrict__ s, const float* __restrict__ Wcat,
    const float* __restrict__ rots, const float* __restrict__ trans,
    float* __restrict__ P)
{
    const int tid = threadIdx.x;
    const int tx = tid & 15, ty = tid >> 4;
    const int n0 = blockIdx.x * 48;
    const int m0 = blockIdx.y * 32;
    __shared__ float As[32][34];
    __shared__ float Bs[32][50];
    __shared__ float rot_lds[32][12];

    if (n0 >= 576) {
        for (int idx = tid; idx < 32 * 12; idx += 256) {
            int r = idx / 12, q = idx % 12;
            rot_lds[r][q] = (q < 9) ? rots[(size_t)(m0 + r) * 9 + q]
                                    : trans[(size_t)(m0 + r) * 3 + q - 9];
        }
    }

    float acc[2][3];
    #pragma unroll
    for (int u = 0; u < 2; ++u)
        #pragma unroll
        for (int v = 0; v < 3; ++v) acc[u][v] = 0.f;

    for (int k0 = 0; k0 < CS; k0 += 32) {
        __syncthreads();
        #pragma unroll
        for (int l = 0; l < 4; ++l) {
            int idx = tid + l * 256;           // 1024 = 32 k x 32 rows
            int kk = idx & 31, r = idx >> 5;
            As[kk][r] = s[(size_t)(m0 + r) * CS + k0 + kk];
        }
        #pragma unroll
        for (int l = 0; l < 6; ++l) {
            int idx = tid + l * 256;           // 1536 = 32 k x 48 cols
            int kk = idx / 48, cc = idx % 48;
            Bs[kk][cc] = Wcat[(size_t)(k0 + kk) * PW + n0 + cc];
        }
        __syncthreads();
        #pragma unroll
        for (int kk = 0; kk < 32; ++kk) {
            const float2 a = *(const float2*)&As[kk][ty * 2];
            const float b0 = Bs[kk][tx * 3], b1 = Bs[kk][tx * 3 + 1], b2 = Bs[kk][tx * 3 + 2];
            acc[0][0] += a.x * b0; acc[0][1] += a.x * b1; acc[0][2] += a.x * b2;
            acc[1][0] += a.y * b0; acc[1][1] += a.y * b1; acc[1][2] += a.y * b2;
        }
    }

    #pragma unroll
    for (int u = 0; u < 2; ++u) {
        float v0 = acc[u][0], v1 = acc[u][1], v2 = acc[u][2];
        if (n0 >= 576) {   // this thread owns exactly one 3-vector
            const float* RT = rot_lds[ty * 2 + u];
            const float p0 = v0, p1 = v1, p2 = v2;
            v0 = RT[0] * p0 + RT[1] * p1 + RT[2] * p2 + RT[9];
            v1 = RT[3] * p0 + RT[4] * p1 + RT[5] * p2 + RT[10];
            v2 = RT[6] * p0 + RT[7] * p1 + RT[8] * p2 + RT[11];
        }
        float* dst = P + (size_t)(m0 + ty * 2 + u) * PW + n0 + tx * 3;
        dst[0] = v0; dst[1] = v1; dst[2] = v2;
    }
}

// ---------------------------------------------------------------------------
// Kernel 2: MFMA flash chunk. grid (512 i, 8 jc), 256 threads (4 waves).
// LDS diet: only zbT[c][j] bf16 tile (16 KB, swizzled). b_ij A-fragments are
// read directly from global z (L1/L2-hot); B-fragments from global WbT16.
// part chunk (u32 stride 1040): u16[0,1536) ohat | [1536,1728) o |
// [1728,2016) ohp ; f32 @u32 1008+h = pm, 1020+h = ps.
// ---------------------------------------------------------------------------
__global__ __launch_bounds__(256) void k_flash(
    const float* __restrict__ z, const ushort* __restrict__ wbt16,
    const float* __restrict__ gamma, const float* __restrict__ P,
    uint* __restrict__ part)
{
    const int i   = blockIdx.x;
    const int jc  = blockIdx.y;
    const int j0  = jc * JB;
    const int tid = threadIdx.x;
    const int wid = tid >> 6, lane = tid & 63;

    __shared__ __align__(16) short zbT[128 * JB];    // 16 KB
    __shared__ __align__(16) short ltb[16 * 64];     // 2 KB
    __shared__ float ltf[16 * 68];                   // 4.35 KB
    __shared__ float q_lds[192];
    __shared__ float qg_lds[144];
    __shared__ float gam_lds[NH];
    __shared__ float pm[NH], ps[NH];

    uint* pb32   = part + ((size_t)i * NCH + jc) * PSTRIDE32;
    ushort* pb16 = (ushort*)pb32;
    float* pbf   = (float*)pb32;

    // ---- staging (zbT only) + b_ij MFMA from global fragments ----
    {
        const float* qrow = P + (size_t)i * PW;
        if (tid < 192) q_lds[tid]  = qrow[tid];
        if (tid < 144) qg_lds[tid] = qrow[576 + tid];
        if (tid < NH)  gam_lds[tid] = gamma[tid];

        // z tile -> zbT[c][j] bf16 (column writes are lane-contiguous)
        const float4* zr = (const float4*)(z + ((size_t)i * NRES + j0 + lane) * CZ + wid * 32);
        float f[32];
        #pragma unroll
        for (int k = 0; k < 8; ++k) {
            const float4 t = zr[k];
            f[k * 4 + 0] = t.x; f[k * 4 + 1] = t.y;
            f[k * 4 + 2] = t.z; f[k * 4 + 3] = t.w;
        }
        #pragma unroll
        for (int m = 0; m < 32; ++m) {
            const int c = wid * 32 + m;
            zbT[c * 64 + (((lane >> 3) ^ (c & 7)) * 8) + (lane & 7)] = (short)f2b(f[m]);
        }
    }
    {
        // b_ij: wave wid = M-tile (16 j); A from global z, B from global WbT16
        const int jrow = wid * 16 + (lane & 15);
        const int hcol = lane & 15;
        const float* za = z + ((size_t)i * NRES + j0 + jrow) * CZ + (lane >> 4) * 8;
        const ushort* wrow = wbt16 + hcol * 128 + (lane >> 4) * 8;
        floatx4 acc = {0.f, 0.f, 0.f, 0.f};
        #pragma unroll
        for (int ks = 0; ks < 4; ++ks) {
            const float4 fa0 = *(const float4*)(za + ks * 32);
            const float4 fa1 = *(const float4*)(za + ks * 32 + 4);
            short8v a;
            a[0] = (short)f2b(fa0.x); a[1] = (short)f2b(fa0.y);
            a[2] = (short)f2b(fa0.z); a[3] = (short)f2b(fa0.w);
            a[4] = (short)f2b(fa1.x); a[5] = (short)f2b(fa1.y);
            a[6] = (short)f2b(fa1.z); a[7] = (short)f2b(fa1.w);
            const short8v b = *(const short8v*)(wrow + ks * 32);
            acc = __builtin_amdgcn_mfma_f32_16x16x32_bf16(a, b, acc, 0, 0, 0);
        }
        #pragma unroll
        for (int r = 0; r < 4; ++r)
            ltf[hcol * 68 + wid * 16 + (lane >> 4) * 4 + r] = acc[r];
    }
    __syncthreads();

    // ---- logits: qk + dist2. thread = (jl = tid&63, wid): 3 heads ----
    {
        const int jl = tid & 63;
        const int j  = j0 + jl;
        const float* krow  = P + (size_t)j * PW + 192;
        const float* kgrow = P + (size_t)j * PW + 720;
        #pragma unroll
        for (int h3 = 0; h3 < 3; ++h3) {
            const int h = wid * 3 + h3;
            const float4* kp = (const float4*)(krow + h * 16);
            const float4* qp = (const float4*)(q_lds + h * 16);
            float as = 0.f;
            #pragma unroll
            for (int u = 0; u < 4; ++u) {
                const float4 kv = kp[u], qv = qp[u];
                as += kv.x * qv.x + kv.y * qv.y + kv.z * qv.z + kv.w * qv.w;
            }
            const float4* kgp = (const float4*)(kgrow + h * 12);
            const float4* qgp = (const float4*)(qg_lds + h * 12);
            float d2 = 0.f;
            #pragma unroll
            for (int u = 0; u < 3; ++u) {
                const float4 av = qgp[u], bv = kgp[u];
                const float dx = av.x - bv.x, dy = av.y - bv.y;
                const float dz = av.z - bv.z, dw = av.w - bv.w;
                d2 += dx * dx + dy * dy + dz * dz + dw * dw;
            }
            const float bij = ltf[h * 68 + jl];
            ltf[h * 68 + jl] = WL_F * (as * 0.25f + bij - HALF_WC_F * gam_lds[h] * d2);
        }
    }
    __syncthreads();

    // ---- chunk softmax (16 lanes/head) + bf16 prob write ----
    if (tid < 192) {
        const int h = tid >> 4, s = tid & 15;
        float4 v = *(const float4*)&ltf[h * 68 + s * 4];
        float m = fmaxf(fmaxf(v.x, v.y), fmaxf(v.z, v.w));
        #pragma unroll
        for (int o = 1; o < 16; o <<= 1) m = fmaxf(m, __shfl_xor(m, o));
        float4 e;
        e.x = __expf(v.x - m); e.y = __expf(v.y - m);
        e.z = __expf(v.z - m); e.w = __expf(v.w - m);
        float sum = e.x + e.y + e.z + e.w;
        #pragma unroll
        for (int o = 1; o < 16; o <<= 1) sum += __shfl_xor(sum, o);
        *(float4*)&ltf[h * 68 + s * 4] = e;
        const uint lo = (uint)f2b(e.x) | ((uint)f2b(e.y) << 16);
        const uint hi = (uint)f2b(e.z) | ((uint)f2b(e.w) << 16);
        uint* dst = (uint*)&ltb[h * 64 + (((s >> 1) ^ (h & 7)) * 8) + (s & 1) * 4];
        dst[0] = lo; dst[1] = hi;
        if (s == 0) { pbf[1008 + h] = m; pbf[1020 + h] = sum; }
    } else {
        const int tt = tid - 192;
        uint* dst = (uint*)&ltb[(12 + (tt >> 4)) * 64 + (tt & 15) * 4];
        dst[0] = 0u; dst[1] = 0u;
    }
    __syncthreads();

    // ---- waves 0-1: o_hat MFMA (M=16h, N=128d, K=64j) ----
    if (wid < 2) {
        const int hrow = lane & 15;
        const int u0 = (lane >> 4), u1 = (lane >> 4) + 4;
        const short8v a0 = *(const short8v*)&ltb[hrow * 64 + ((u0 ^ (hrow & 7)) * 8)];
        const short8v a1 = *(const short8v*)&ltb[hrow * 64 + ((u1 ^ (hrow & 7)) * 8)];
        #pragma unroll
        for (int t = 0; t < 4; ++t) {
            const int nt = wid * 4 + t;
            const int d  = nt * 16 + (lane & 15);
            const short8v b0 = *(const short8v*)&zbT[d * 64 + ((u0 ^ (d & 7)) * 8)];
            const short8v b1 = *(const short8v*)&zbT[d * 64 + ((u1 ^ (d & 7)) * 8)];
            floatx4 acc = {0.f, 0.f, 0.f, 0.f};
            acc = __builtin_amdgcn_mfma_f32_16x16x32_bf16(a0, b0, acc, 0, 0, 0);
            acc = __builtin_amdgcn_mfma_f32_16x16x32_bf16(a1, b1, acc, 0, 0, 0);
            #pragma unroll
            for (int r = 0; r < 4; ++r) {
                const int h = (lane >> 4) * 4 + r;
                if (h < NH) pb16[h * 128 + d] = f2b(acc[r]);
            }
        }
    } else {
        // ---- waves 2-3: o / o_hp vector from P (unnormalized e in ltf) ----
        const int t2 = tid - 128;
        if (t2 < 120) {
            int h, off16;
            const float* base;
            if (t2 < 48) { h = t2 >> 2; base = P + (size_t)j0 * PW + 384 + t2 * 4; off16 = 1536 + t2 * 4; }
            else { const int cc = t2 - 48; h = cc / 6; base = P + (size_t)j0 * PW + 864 + cc * 4; off16 = 1728 + cc * 4; }
            float ax = 0.f, ay = 0.f, az = 0.f, aw = 0.f;
            #pragma unroll 4
            for (int jj = 0; jj < JB; ++jj) {
                const float e = ltf[h * 68 + jj];
                const float4 v = *(const float4*)(base + (size_t)jj * PW);
                ax += e * v.x; ay += e * v.y; az += e * v.z; aw += e * v.w;
            }
            uint* dst = (uint*)&pb16[off16];
            dst[0] = (uint)f2b(ax) | ((uint)f2b(ay) << 16);
            dst[1] = (uint)f2b(az) | ((uint)f2b(aw) << 16);
        }
    }
}

// ---------------------------------------------------------------------------
// Kernel 3: combine 8 chunks -> cat row. grid 512, 256 threads.
// ---------------------------------------------------------------------------
__global__ __launch_bounds__(256) void k_combine(
    const uint* __restrict__ part, const float* __restrict__ rots,
    const float* __restrict__ trans, float* __restrict__ cat)
{
    const int i   = blockIdx.x;
    const int tid = threadIdx.x;
    __shared__ float wgt[NCH][NH];
    __shared__ float ohp[288];

    const uint* base = part + (size_t)i * NCH * PSTRIDE32;
    if (tid < NH) {
        const int h = tid;
        float mm[NCH];
        float M = -1e30f;
        #pragma unroll
        for (int c = 0; c < NCH; ++c) {
            mm[c] = ((const float*)(base + c * PSTRIDE32))[1008 + h];
            M = fmaxf(M, mm[c]);
        }
        float S = 0.f;
        #pragma unroll
        for (int c = 0; c < NCH; ++c) {
            const float w = __expf(mm[c] - M);
            S += w * ((const float*)(base + c * PSTRIDE32))[1020 + h];
            wgt[c][h] = w;
        }
        const float inv = 1.0f / S;
        #pragma unroll
        for (int c = 0; c < NCH; ++c) wgt[c][h] *= inv;
    }
    __syncthreads();

    float* crow = cat + (size_t)i * 2112;
    for (int idx2 = tid; idx2 < 768; idx2 += 256) {      // ohat: 1536 u16 as uint
        const int h = idx2 >> 6;
        float v0 = 0.f, v1 = 0.f;
        #pragma unroll
        for (int c = 0; c < NCH; ++c) {
            const uint u = base[c * PSTRIDE32 + idx2];
            const float w = wgt[c][h];
            v0 += b2f((ushort)u) * w;
            v1 += b2f((ushort)(u >> 16)) * w;
        }
        *(float2*)&crow[idx2 * 2] = make_float2(v0, v1);
    }
    if (tid < 96) {                                       // o: 192 u16
        const int h = tid >> 3;
        float v0 = 0.f, v1 = 0.f;
        #pragma unroll
        for (int c = 0; c < NCH; ++c) {
            const uint u = base[c * PSTRIDE32 + 768 + tid];
            const float w = wgt[c][h];
            v0 += b2f((ushort)u) * w;
            v1 += b2f((ushort)(u >> 16)) * w;
        }
        *(float2*)&crow[1536 + tid * 2] = make_float2(v0, v1);
    }
    if (tid < 144) {                                      // ohp: 288 u16
        const int h = tid / 12;
        float v0 = 0.f, v1 = 0.f;
        #pragma unroll
        for (int c = 0; c < NCH; ++c) {
            const uint u = base[c * PSTRIDE32 + 864 + tid];
            const float w = wgt[c][h];
            v0 += b2f((ushort)u) * w;
            v1 += b2f((ushort)(u >> 16)) * w;
        }
        ohp[tid * 2] = v0; ohp[tid * 2 + 1] = v1;
    }
    __syncthreads();

    if (tid < 96) {
        const int h = tid >> 3, p = tid & 7;
        float R[9];
        #pragma unroll
        for (int k = 0; k < 9; ++k) R[k] = rots[(size_t)i * 9 + k];
        const float g0 = ohp[h * 24 + p * 3 + 0] - trans[(size_t)i * 3 + 0];
        const float g1 = ohp[h * 24 + p * 3 + 1] - trans[(size_t)i * 3 + 1];
        const float g2 = ohp[h * 24 + p * 3 + 2] - trans[(size_t)i * 3 + 2];
        const float oy0 = R[0] * g0 + R[3] * g1 + R[6] * g2;
        const float oy1 = R[1] * g0 + R[4] * g1 + R[7] * g2;
        const float oy2 = R[2] * g0 + R[5] * g1 + R[8] * g2;
        crow[1728 + h * 24 + p * 3 + 0] = oy0;
        crow[1728 + h * 24 + p * 3 + 1] = oy1;
        crow[1728 + h * 24 + p * 3 + 2] = oy2;
        crow[2016 + h * 8 + p] = sqrtf(oy0 * oy0 + oy1 * oy1 + oy2 * oy2);
    }
}

// ---------------------------------------------------------------------------
// Kernel 4: out-proj partials. grid (3 ctile, 64 rtile, 11 ksplit of 192).
// ---------------------------------------------------------------------------
__global__ __launch_bounds__(256) void k_out(
    const float* __restrict__ cat, const float* __restrict__ Wout,
    float* __restrict__ opart)
{
    const int tid = threadIdx.x;
    const int cp  = tid & 63;
    const int qd  = tid >> 6;
    const int c0  = blockIdx.x * 128 + cp * 2;
    const int i0  = blockIdx.y * 8;
    const int k0  = blockIdx.z * 192;
    const int r0  = qd * 2, r1 = r0 + 1;
    __shared__ float lds[8][65];
    float a00 = 0.f, a01 = 0.f, a10 = 0.f, a11 = 0.f;
    for (int kc = k0; kc < k0 + 192; kc += 64) {
        __syncthreads();
        for (int idx = tid; idx < 512; idx += 256) {
            int r = idx >> 6, kk = idx & 63;
            lds[r][kk] = cat[(size_t)(i0 + r) * 2112 + kc + kk];
        }
        __syncthreads();
        #pragma unroll 8
        for (int kk = 0; kk < 64; ++kk) {
            const float2 w = *(const float2*)(Wout + (size_t)(kc + kk) * 384 + c0);
            float l0 = lds[r0][kk], l1 = lds[r1][kk];
            a00 += l0 * w.x; a01 += l0 * w.y;
            a10 += l1 * w.x; a11 += l1 * w.y;
        }
    }
    float* ob = opart + (size_t)blockIdx.z * 512 * 384;
    ob[(size_t)(i0 + r0) * 384 + c0]     = a00;
    ob[(size_t)(i0 + r0) * 384 + c0 + 1] = a01;
    ob[(size_t)(i0 + r1) * 384 + c0]     = a10;
    ob[(size_t)(i0 + r1) * 384 + c0 + 1] = a11;
}

// Kernel 5: reduce 11 k-partials + bias.
__global__ __launch_bounds__(256) void k_outred(
    const float* __restrict__ opart, const float* __restrict__ bout,
    float* __restrict__ out)
{
    const int e4 = blockIdx.x * 256 + threadIdx.x;
    const float4* p = (const float4*)opart;
    const float4 b = ((const float4*)bout)[e4 % 96];
    float4 r = b;
    #pragma unroll
    for (int k = 0; k < KSPLIT; ++k) {
        const float4 v = p[e4 + k * 49152];
        r.x += v.x; r.y += v.y; r.z += v.z; r.w += v.w;
    }
    ((float4*)out)[e4] = r;
}

// ---------------------------------------------------------------------------
extern "C" void kernel_launch(void* const* d_in, const int* in_sizes, int n_in,
                              void* d_out, int out_size, void* d_ws, size_t ws_size,
                              hipStream_t stream)
{
    const float* s_i   = (const float*)d_in[0];
    const float* z_ij  = (const float*)d_in[1];
    const float* rots  = (const float*)d_in[2];
    const float* trans = (const float*)d_in[3];
    const float* Wq    = (const float*)d_in[4];
    const float* Wk    = (const float*)d_in[5];
    const float* Wv    = (const float*)d_in[6];
    const float* Wqp   = (const float*)d_in[7];
    const float* Wkp   = (const float*)d_in[8];
    const float* Wvp   = (const float*)d_in[9];
    const float* Wb    = (const float*)d_in[10];
    const float* gamma = (const float*)d_in[11];
    const float* Wout  = (const float*)d_in[12];
    const float* bout  = (const float*)d_in[13];
    float* ws = (float*)d_ws;
    float*  wcat  = ws;                          // 442368 f
    float*  P     = ws + 442368;                 // 589824 f
    uint*   part  = (uint*)(P + 589824);         // 512*8*1040 u32
    float*  opart = (float*)part;                // aliased: part consumed by
                                                 // k_combine before k_out writes
    float*  cat   = (float*)(part + (size_t)512 * NCH * PSTRIDE32);  // 1081344 f
    ushort* wbt16 = (ushort*)(cat + 1081344);    // 2048 u16
    float*  out   = (float*)d_out;

    hipLaunchKernelGGL(k_pack, dim3(384), dim3(256), 0, stream,
                       Wq, Wk, Wv, Wqp, Wkp, Wvp, Wb, wcat, wbt16);
    hipLaunchKernelGGL(k_gemm, dim3(24, 16), dim3(256), 0, stream,
                       s_i, wcat, rots, trans, P);
    hipLaunchKernelGGL(k_flash, dim3(512, NCH), dim3(256), 0, stream,
                       z_ij, wbt16, gamma, P, part);
    hipLaunchKernelGGL(k_combine, dim3(512), dim3(256), 0, stream,
                       part, rots, trans, cat);
    hipLaunchKernelGGL(k_out, dim3(3, 64, KSPLIT), dim3(256), 0, stream,
                       cat, Wout, opart);
    hipLaunchKernelGGL(k_outred, dim3(192), dim3(256), 0, stream,
                       opart, bout, out);
}

// Round 8
// 173.493 us; speedup vs baseline: 1.4389x; 1.1667x over previous
//
#include <hip/hip_runtime.h>
#include <hip/hip_bf16.h>
#include <math.h>

#define NRES 512
#define CS   384
#define CZ   128
#define NH   12
#define PW   1152   // packed projection width
#define JB   64     // j per flash block
#define NCH  8      // chunks = NRES/JB
#define PSTRIDE32 1040  // part chunk stride in u32 units
#define KSPLIT 11   // k_out K splits (2112 = 11*192)
#define KAW  352    // Kfull row width (11 * 32)

static constexpr float WL_F      = 0.57735026918962576f;   // sqrt(1/3)
static constexpr float HALF_WC_F = 0.11785113019775792f;   // 0.5*sqrt(2/(9*4))

typedef __attribute__((ext_vector_type(8))) short short8v;
typedef __attribute__((ext_vector_type(4))) float floatx4;

__device__ __forceinline__ ushort f2b(float f) {
    union { float f; uint u; } v; v.f = f;
    return (ushort)((v.u + 0x7FFFu + ((v.u >> 16) & 1u)) >> 16);
}
__device__ __forceinline__ float b2f(ushort b) {
    union { uint u; float f; } v; v.u = ((uint)b) << 16; return v.f;
}

// ---------------------------------------------------------------------------
// Kernel 0: pack Wcat[384][1152]; block 0 packs WbT16[16][128] bf16 scaled
// by W_L (rows >= 12 zero) — consumed only as the z-block of BfT in k_flash.
// ---------------------------------------------------------------------------
__global__ __launch_bounds__(256) void k_pack(
    const float* __restrict__ Wq, const float* __restrict__ Wk,
    const float* __restrict__ Wv, const float* __restrict__ Wqp,
    const float* __restrict__ Wkp, const float* __restrict__ Wvp,
    const float* __restrict__ Wb,
    float* __restrict__ Wcat, ushort* __restrict__ wbt16)
{
    const int c = blockIdx.x;
    for (int col = threadIdx.x; col < PW; col += 256) {
        float v;
        if (col < 192)      v = Wq [(size_t)c * 192 + col];
        else if (col < 384) v = Wk [(size_t)c * 192 + col - 192];
        else if (col < 576) v = Wv [(size_t)c * 192 + col - 384];
        else if (col < 720) v = Wqp[(size_t)c * 144 + col - 576];
        else if (col < 864) v = Wkp[(size_t)c * 144 + col - 720];
        else                v = Wvp[(size_t)c * 288 + col - 864];
        Wcat[(size_t)c * PW + col] = v;
    }
    if (blockIdx.x == 0) {
        for (int idx = threadIdx.x; idx < 16 * 128; idx += 256) {
            const int h = idx >> 7, cc = idx & 127;
            wbt16[idx] = (h < NH) ? f2b(WL_F * Wb[(size_t)cc * NH + h]) : (ushort)0;
        }
    }
}

// ---------------------------------------------------------------------------
// Kernel 1: P[512][1152] = s @ Wcat, rigid transform fused for cols >= 576.
// ---------------------------------------------------------------------------
__global__ __launch_bounds__(256) void k_gemm(
    const float* __restrict__ s, const float* __restrict__ Wcat,
    const float* __restrict__ rots, const float* __restrict__ trans,
    float* __restrict__ P)
{
    const int tid = threadIdx.x;
    const int tx = tid & 15, ty = tid >> 4;
    const int n0 = blockIdx.x * 48;
    const int m0 = blockIdx.y * 32;
    __shared__ float As[32][34];
    __shared__ float Bs[32][50];
    __shared__ float rot_lds[32][12];

    if (n0 >= 576) {
        for (int idx = tid; idx < 32 * 12; idx += 256) {
            int r = idx / 12, q = idx % 12;
            rot_lds[r][q] = (q < 9) ? rots[(size_t)(m0 + r) * 9 + q]
                                    : trans[(size_t)(m0 + r) * 3 + q - 9];
        }
    }

    float acc[2][3];
    #pragma unroll
    for (int u = 0; u < 2; ++u)
        #pragma unroll
        for (int v = 0; v < 3; ++v) acc[u][v] = 0.f;

    for (int k0 = 0; k0 < CS; k0 += 32) {
        __syncthreads();
        #pragma unroll
        for (int l = 0; l < 4; ++l) {
            int idx = tid + l * 256;
            int kk = idx & 31, r = idx >> 5;
            As[kk][r] = s[(size_t)(m0 + r) * CS + k0 + kk];
        }
        #pragma unroll
        for (int l = 0; l < 6; ++l) {
            int idx = tid + l * 256;
            int kk = idx / 48, cc = idx % 48;
            Bs[kk][cc] = Wcat[(size_t)(k0 + kk) * PW + n0 + cc];
        }
        __syncthreads();
        #pragma unroll
        for (int kk = 0; kk < 32; ++kk) {
            const float2 a = *(const float2*)&As[kk][ty * 2];
            const float b0 = Bs[kk][tx * 3], b1 = Bs[kk][tx * 3 + 1], b2 = Bs[kk][tx * 3 + 2];
            acc[0][0] += a.x * b0; acc[0][1] += a.x * b1; acc[0][2] += a.x * b2;
            acc[1][0] += a.y * b0; acc[1][1] += a.y * b1; acc[1][2] += a.y * b2;
        }
    }

    #pragma unroll
    for (int u = 0; u < 2; ++u) {
        float v0 = acc[u][0], v1 = acc[u][1], v2 = acc[u][2];
        if (n0 >= 576) {
            const float* RT = rot_lds[ty * 2 + u];
            const float p0 = v0, p1 = v1, p2 = v2;
            v0 = RT[0] * p0 + RT[1] * p1 + RT[2] * p2 + RT[9];
            v1 = RT[3] * p0 + RT[4] * p1 + RT[5] * p2 + RT[10];
            v2 = RT[6] * p0 + RT[7] * p1 + RT[8] * p2 + RT[11];
        }
        float* dst = P + (size_t)(m0 + ty * 2 + u) * PW + n0 + tx * 3;
        dst[0] = v0; dst[1] = v1; dst[2] = v2;
    }
}

// ---------------------------------------------------------------------------
// Kernel 1b: Kfull[512][352] bf16 augmented K rows:
// [0,192) k | [192,336) kg | [336,348) nj_h | 348: 1 | pad
// ---------------------------------------------------------------------------
__global__ __launch_bounds__(128) void k_ka(
    const float* __restrict__ P, ushort* __restrict__ Kfull)
{
    const int j = blockIdx.x;
    const int tid = threadIdx.x;
    __shared__ float njs[NH];
    const float* kr  = P + (size_t)j * PW + 192;
    const float* kgr = P + (size_t)j * PW + 720;
    if (tid < NH) {
        float s = 0.f;
        #pragma unroll
        for (int e = 0; e < 12; ++e) { const float v = kgr[tid * 12 + e]; s += v * v; }
        njs[tid] = s;
    }
    __syncthreads();
    ushort* dst = Kfull + (size_t)j * KAW;
    for (int t = tid; t < KAW; t += 128) {
        float v;
        if (t < 192)       v = kr[t];
        else if (t < 336)  v = kgr[t - 192];
        else if (t < 348)  v = njs[t - 336];
        else if (t == 348) v = 1.0f;
        else               v = 0.f;
        dst[t] = f2b(v);
    }
}

// ---------------------------------------------------------------------------
// Kernel 2: MFMA flash chunk. grid (512 i, 8 jc), 256 threads (4 waves).
// Logits = ONE fused MFMA chain (15 steps of 16x16x32):
//   steps 0..10: A = Kfull rows (global bf16), B = BfT (LDS, Q-side)
//   steps 11..14: A = z rows (global f32 -> bf16), B = BfT z-block (WL*Wb)
// acc[j][h] is the complete logit. Then softmax, o_hat MFMA (all 4 waves),
// o/o_hp vector split into 2 j-halves with LDS reduce.
// ---------------------------------------------------------------------------
__global__ __launch_bounds__(256) void k_flash(
    const float* __restrict__ z, const ushort* __restrict__ wbt16,
    const float* __restrict__ gamma, const float* __restrict__ P,
    const ushort* __restrict__ Kfull, uint* __restrict__ part)
{
    const int i   = blockIdx.x;
    const int jc  = blockIdx.y;
    const int j0  = jc * JB;
    const int tid = threadIdx.x;
    const int wid = tid >> 6, lane = tid & 63;

    __shared__ __align__(16) short zbT[128 * JB];    // 16 KB
    __shared__ __align__(16) short BfT[16 * 488];    // 15.6 KB, B^T [n=16][k=488]
    __shared__ __align__(16) short ltb[16 * 64];     // 2 KB
    __shared__ float ltf[16 * 68];                   // 4.35 KB
    __shared__ float pm[NH], ps[NH];

    uint* pb32   = part + ((size_t)i * NCH + jc) * PSTRIDE32;
    ushort* pb16 = (ushort*)pb32;
    float* pbf   = (float*)pb32;

    // ---- phase 1: zero BfT ----
    for (int idx = tid; idx < 16 * 488 / 2; idx += 256) ((uint*)BfT)[idx] = 0u;
    __syncthreads();

    // ---- phase 2: zbT staging + BfT scatter ----
    {
        const float4* zr = (const float4*)(z + ((size_t)i * NRES + j0 + lane) * CZ + wid * 32);
        float f[32];
        #pragma unroll
        for (int k = 0; k < 8; ++k) {
            const float4 t = zr[k];
            f[k * 4 + 0] = t.x; f[k * 4 + 1] = t.y;
            f[k * 4 + 2] = t.z; f[k * 4 + 3] = t.w;
        }
        #pragma unroll
        for (int m = 0; m < 32; ++m) {
            const int c = wid * 32 + m;
            zbT[c * 64 + (((lane >> 3) ^ (c & 7)) * 8) + (lane & 7)] = (short)f2b(f[m]);
        }
    }
    {
        const float* prow = P + (size_t)i * PW;
        for (int t = tid; t < 360; t += 256) {
            if (t < 192) {
                const int h = t >> 4;
                BfT[h * 488 + t] = (short)f2b(0.25f * WL_F * prow[t]);
            } else if (t < 336) {
                const int e = t - 192, h = e / 12;
                BfT[h * 488 + t] =
                    (short)f2b(2.f * HALF_WC_F * WL_F * gamma[h] * prow[576 + e]);
            } else if (t < 348) {
                const int h = t - 336;
                BfT[h * 488 + t] = (short)f2b(-HALF_WC_F * WL_F * gamma[h]);
            } else {
                const int h = t - 348;
                float s = 0.f;
                #pragma unroll
                for (int e = 0; e < 12; ++e) {
                    const float v = prow[576 + h * 12 + e];
                    s += v * v;
                }
                BfT[h * 488 + 348] = (short)f2b(-HALF_WC_F * WL_F * gamma[h] * s);
            }
        }
        for (int idx = tid; idx < 1024; idx += 256) {
            const int h = idx >> 6, c2 = idx & 63;
            *(uint*)&BfT[h * 488 + 352 + c2 * 2] = ((const uint*)wbt16)[h * 64 + c2];
        }
    }
    __syncthreads();

    // ---- phase 3: fused logits MFMA (15 K-steps) ----
    {
        const int jb = wid * 16 + (lane & 15);
        const int n  = lane & 15;
        const int ko = (lane >> 4) * 8;
        const ushort* arow = Kfull + (size_t)(j0 + jb) * KAW + ko;
        const short*  brow = &BfT[n * 488 + ko];
        const float*  za   = z + ((size_t)i * NRES + j0 + jb) * CZ + ko;
        floatx4 acc = {0.f, 0.f, 0.f, 0.f};
        #pragma unroll
        for (int st = 0; st < 11; ++st) {
            const short8v a = *(const short8v*)(arow + st * 32);
            const short8v b = *(const short8v*)(brow + st * 32);
            acc = __builtin_amdgcn_mfma_f32_16x16x32_bf16(a, b, acc, 0, 0, 0);
        }
        #pragma unroll
        for (int st = 0; st < 4; ++st) {
            const float4 f0 = *(const float4*)(za + st * 32);
            const float4 f1 = *(const float4*)(za + st * 32 + 4);
            short8v a;
            a[0] = (short)f2b(f0.x); a[1] = (short)f2b(f0.y);
            a[2] = (short)f2b(f0.z); a[3] = (short)f2b(f0.w);
            a[4] = (short)f2b(f1.x); a[5] = (short)f2b(f1.y);
            a[6] = (short)f2b(f1.z); a[7] = (short)f2b(f1.w);
            const short8v b = *(const short8v*)(brow + (11 + st) * 32);
            acc = __builtin_amdgcn_mfma_f32_16x16x32_bf16(a, b, acc, 0, 0, 0);
        }
        #pragma unroll
        for (int r = 0; r < 4; ++r)
            ltf[n * 68 + wid * 16 + (lane >> 4) * 4 + r] = acc[r];
    }
    __syncthreads();

    // ---- phase 4: chunk softmax (16 lanes/head) + bf16 prob write ----
    if (tid < 192) {
        const int h = tid >> 4, s = tid & 15;
        float4 v = *(const float4*)&ltf[h * 68 + s * 4];
        float m = fmaxf(fmaxf(v.x, v.y), fmaxf(v.z, v.w));
        #pragma unroll
        for (int o = 1; o < 16; o <<= 1) m = fmaxf(m, __shfl_xor(m, o));
        float4 e;
        e.x = __expf(v.x - m); e.y = __expf(v.y - m);
        e.z = __expf(v.z - m); e.w = __expf(v.w - m);
        float sum = e.x + e.y + e.z + e.w;
        #pragma unroll
        for (int o = 1; o < 16; o <<= 1) sum += __shfl_xor(sum, o);
        *(float4*)&ltf[h * 68 + s * 4] = e;
        const uint lo = (uint)f2b(e.x) | ((uint)f2b(e.y) << 16);
        const uint hi = (uint)f2b(e.z) | ((uint)f2b(e.w) << 16);
        uint* dst = (uint*)&ltb[h * 64 + (((s >> 1) ^ (h & 7)) * 8) + (s & 1) * 4];
        dst[0] = lo; dst[1] = hi;
        if (s == 0) { pm[h] = m; ps[h] = sum; }
    } else {
        const int tt = tid - 192;
        uint* dst = (uint*)&ltb[(12 + (tt >> 4)) * 64 + (tt & 15) * 4];
        dst[0] = 0u; dst[1] = 0u;
    }
    __syncthreads();

    // ---- phase 5a: o_hat MFMA — all 4 waves, 2 N-tiles each ----
    {
        const int hrow = lane & 15;
        const int u0 = (lane >> 4), u1 = u0 + 4;
        const short8v a0 = *(const short8v*)&ltb[hrow * 64 + ((u0 ^ (hrow & 7)) * 8)];
        const short8v a1 = *(const short8v*)&ltb[hrow * 64 + ((u1 ^ (hrow & 7)) * 8)];
        #pragma unroll
        for (int t = 0; t < 2; ++t) {
            const int nt = wid * 2 + t;
            const int d  = nt * 16 + (lane & 15);
            const short8v b0 = *(const short8v*)&zbT[d * 64 + ((u0 ^ (d & 7)) * 8)];
            const short8v b1 = *(const short8v*)&zbT[d * 64 + ((u1 ^ (d & 7)) * 8)];
            floatx4 acc = {0.f, 0.f, 0.f, 0.f};
            acc = __builtin_amdgcn_mfma_f32_16x16x32_bf16(a0, b0, acc, 0, 0, 0);
            acc = __builtin_amdgcn_mfma_f32_16x16x32_bf16(a1, b1, acc, 0, 0, 0);
            #pragma unroll
            for (int r = 0; r < 4; ++r) {
                const int h = (lane >> 4) * 4 + r;
                if (h < NH) pb16[h * 128 + d] = f2b(acc[r]);
            }
        }
    }

    // ---- phase 5b: o / o_hp — 240 slots = 2 j-halves x 120 cols ----
    {
        float4* halfacc = (float4*)BfT;   // BfT dead after logits phase
        if (tid < 240) {
            const int half = tid / 120, col = tid % 120;
            int h;
            const float* base;
            if (col < 48) { h = col >> 2;               base = P + (size_t)j0 * PW + 384 + col * 4; }
            else          { const int cc = col - 48; h = cc / 6; base = P + (size_t)j0 * PW + 864 + cc * 4; }
            base += (size_t)(half * 32) * PW;
            const float* er = &ltf[h * 68 + half * 32];
            float ax = 0.f, ay = 0.f, az = 0.f, aw = 0.f;
            #pragma unroll 4
            for (int jj = 0; jj < 32; ++jj) {
                const float e = er[jj];
                const float4 v = *(const float4*)(base + (size_t)jj * PW);
                ax += e * v.x; ay += e * v.y; az += e * v.z; aw += e * v.w;
            }
            halfacc[tid] = make_float4(ax, ay, az, aw);
        }
        __syncthreads();
        if (tid < 120) {
            const float4 s0 = halfacc[tid], s1 = halfacc[tid + 120];
            const int off16 = (tid < 48) ? 1536 + tid * 4 : 1728 + (tid - 48) * 4;
            uint* dst = (uint*)&pb16[off16];
            dst[0] = (uint)f2b(s0.x + s1.x) | ((uint)f2b(s0.y + s1.y) << 16);
            dst[1] = (uint)f2b(s0.z + s1.z) | ((uint)f2b(s0.w + s1.w) << 16);
        }
        if (tid < NH) { pbf[1008 + tid] = pm[tid]; pbf[1020 + tid] = ps[tid]; }
    }
}

// ---------------------------------------------------------------------------
// Kernel 3: combine 8 chunks -> cat row. grid 512, 256 threads.
// ---------------------------------------------------------------------------
__global__ __launch_bounds__(256) void k_combine(
    const uint* __restrict__ part, const float* __restrict__ rots,
    const float* __restrict__ trans, float* __restrict__ cat)
{
    const int i   = blockIdx.x;
    const int tid = threadIdx.x;
    __shared__ float wgt[NCH][NH];
    __shared__ float ohp[288];

    const uint* base = part + (size_t)i * NCH * PSTRIDE32;
    if (tid < NH) {
        const int h = tid;
        float mm[NCH];
        float M = -1e30f;
        #pragma unroll
        for (int c = 0; c < NCH; ++c) {
            mm[c] = ((const float*)(base + c * PSTRIDE32))[1008 + h];
            M = fmaxf(M, mm[c]);
        }
        float S = 0.f;
        #pragma unroll
        for (int c = 0; c < NCH; ++c) {
            const float w = __expf(mm[c] - M);
            S += w * ((const float*)(base + c * PSTRIDE32))[1020 + h];
            wgt[c][h] = w;
        }
        const float inv = 1.0f / S;
        #pragma unroll
        for (int c = 0; c < NCH; ++c) wgt[c][h] *= inv;
    }
    __syncthreads();

    float* crow = cat + (size_t)i * 2112;
    for (int idx2 = tid; idx2 < 768; idx2 += 256) {
        const int h = idx2 >> 6;
        float v0 = 0.f, v1 = 0.f;
        #pragma unroll
        for (int c = 0; c < NCH; ++c) {
            const uint u = base[c * PSTRIDE32 + idx2];
            const float w = wgt[c][h];
            v0 += b2f((ushort)u) * w;
            v1 += b2f((ushort)(u >> 16)) * w;
        }
        *(float2*)&crow[idx2 * 2] = make_float2(v0, v1);
    }
    if (tid < 96) {
        const int h = tid >> 3;
        float v0 = 0.f, v1 = 0.f;
        #pragma unroll
        for (int c = 0; c < NCH; ++c) {
            const uint u = base[c * PSTRIDE32 + 768 + tid];
            const float w = wgt[c][h];
            v0 += b2f((ushort)u) * w;
            v1 += b2f((ushort)(u >> 16)) * w;
        }
        *(float2*)&crow[1536 + tid * 2] = make_float2(v0, v1);
    }
    if (tid < 144) {
        const int h = tid / 12;
        float v0 = 0.f, v1 = 0.f;
        #pragma unroll
        for (int c = 0; c < NCH; ++c) {
            const uint u = base[c * PSTRIDE32 + 864 + tid];
            const float w = wgt[c][h];
            v0 += b2f((ushort)u) * w;
            v1 += b2f((ushort)(u >> 16)) * w;
        }
        ohp[tid * 2] = v0; ohp[tid * 2 + 1] = v1;
    }
    __syncthreads();

    if (tid < 96) {
        const int h = tid >> 3, p = tid & 7;
        float R[9];
        #pragma unroll
        for (int k = 0; k < 9; ++k) R[k] = rots[(size_t)i * 9 + k];
        const float g0 = ohp[h * 24 + p * 3 + 0] - trans[(size_t)i * 3 + 0];
        const float g1 = ohp[h * 24 + p * 3 + 1] - trans[(size_t)i * 3 + 1];
        const float g2 = ohp[h * 24 + p * 3 + 2] - trans[(size_t)i * 3 + 2];
        const float oy0 = R[0] * g0 + R[3] * g1 + R[6] * g2;
        const float oy1 = R[1] * g0 + R[4] * g1 + R[7] * g2;
        const float oy2 = R[2] * g0 + R[5] * g1 + R[8] * g2;
        crow[1728 + h * 24 + p * 3 + 0] = oy0;
        crow[1728 + h * 24 + p * 3 + 1] = oy1;
        crow[1728 + h * 24 + p * 3 + 2] = oy2;
        crow[2016 + h * 8 + p] = sqrtf(oy0 * oy0 + oy1 * oy1 + oy2 * oy2);
    }
}

// ---------------------------------------------------------------------------
// Kernel 4: out-proj partials. grid (3 ctile, 64 rtile, 11 ksplit of 192).
// ---------------------------------------------------------------------------
__global__ __launch_bounds__(256) void k_out(
    const float* __restrict__ cat, const float* __restrict__ Wout,
    float* __restrict__ opart)
{
    const int tid = threadIdx.x;
    const int cp  = tid & 63;
    const int qd  = tid >> 6;
    const int c0  = blockIdx.x * 128 + cp * 2;
    const int i0  = blockIdx.y * 8;
    const int k0  = blockIdx.z * 192;
    const int r0  = qd * 2, r1 = r0 + 1;
    __shared__ float lds[8][65];
    float a00 = 0.f, a01 = 0.f, a10 = 0.f, a11 = 0.f;
    for (int kc = k0; kc < k0 + 192; kc += 64) {
        __syncthreads();
        for (int idx = tid; idx < 512; idx += 256) {
            int r = idx >> 6, kk = idx & 63;
            lds[r][kk] = cat[(size_t)(i0 + r) * 2112 + kc + kk];
        }
        __syncthreads();
        #pragma unroll 8
        for (int kk = 0; kk < 64; ++kk) {
            const float2 w = *(const float2*)(Wout + (size_t)(kc + kk) * 384 + c0);
            float l0 = lds[r0][kk], l1 = lds[r1][kk];
            a00 += l0 * w.x; a01 += l0 * w.y;
            a10 += l1 * w.x; a11 += l1 * w.y;
        }
    }
    float* ob = opart + (size_t)blockIdx.z * 512 * 384;
    ob[(size_t)(i0 + r0) * 384 + c0]     = a00;
    ob[(size_t)(i0 + r0) * 384 + c0 + 1] = a01;
    ob[(size_t)(i0 + r1) * 384 + c0]     = a10;
    ob[(size_t)(i0 + r1) * 384 + c0 + 1] = a11;
}

// Kernel 5: reduce 11 k-partials + bias.
__global__ __launch_bounds__(256) void k_outred(
    const float* __restrict__ opart, const float* __restrict__ bout,
    float* __restrict__ out)
{
    const int e4 = blockIdx.x * 256 + threadIdx.x;
    const float4* p = (const float4*)opart;
    const float4 b = ((const float4*)bout)[e4 % 96];
    float4 r = b;
    #pragma unroll
    for (int k = 0; k < KSPLIT; ++k) {
        const float4 v = p[e4 + k * 49152];
        r.x += v.x; r.y += v.y; r.z += v.z; r.w += v.w;
    }
    ((float4*)out)[e4] = r;
}

// ---------------------------------------------------------------------------
extern "C" void kernel_launch(void* const* d_in, const int* in_sizes, int n_in,
                              void* d_out, int out_size, void* d_ws, size_t ws_size,
                              hipStream_t stream)
{
    const float* s_i   = (const float*)d_in[0];
    const float* z_ij  = (const float*)d_in[1];
    const float* rots  = (const float*)d_in[2];
    const float* trans = (const float*)d_in[3];
    const float* Wq    = (const float*)d_in[4];
    const float* Wk    = (const float*)d_in[5];
    const float* Wv    = (const float*)d_in[6];
    const float* Wqp   = (const float*)d_in[7];
    const float* Wkp   = (const float*)d_in[8];
    const float* Wvp   = (const float*)d_in[9];
    const float* Wb    = (const float*)d_in[10];
    const float* gamma = (const float*)d_in[11];
    const float* Wout  = (const float*)d_in[12];
    const float* bout  = (const float*)d_in[13];
    float* ws = (float*)d_ws;
    float*  wcat  = ws;                          // 442368 f
    float*  P     = ws + 442368;                 // 589824 f
    uint*   part  = (uint*)(P + 589824);         // 512*8*1040 u32
    float*  opart = (float*)part;                // aliased (sequenced)
    float*  cat   = (float*)(part + (size_t)512 * NCH * PSTRIDE32);  // 1081344 f
    ushort* wbt16 = (ushort*)(cat + 1081344);    // 2048 u16
    ushort* kfull = wbt16 + 2048;                // 512*352 u16
    float*  out   = (float*)d_out;

    hipLaunchKernelGGL(k_pack, dim3(384), dim3(256), 0, stream,
                       Wq, Wk, Wv, Wqp, Wkp, Wvp, Wb, wcat, wbt16);
    hipLaunchKernelGGL(k_gemm, dim3(24, 16), dim3(256), 0, stream,
                       s_i, wcat, rots, trans, P);
    hipLaunchKernelGGL(k_ka, dim3(512), dim3(128), 0, stream, P, kfull);
    hipLaunchKernelGGL(k_flash, dim3(512, NCH), dim3(256), 0, stream,
                       z_ij, wbt16, gamma, P, kfull, part);
    hipLaunchKernelGGL(k_combine, dim3(512), dim3(256), 0, stream,
                       part, rots, trans, cat);
    hipLaunchKernelGGL(k_out, dim3(3, 64, KSPLIT), dim3(256), 0, stream,
                       cat, Wout, opart);
    hipLaunchKernelGGL(k_outred, dim3(192), dim3(256), 0, stream,
                       opart, bout, out);
}